// Round 1
// baseline (368.814 us; speedup 1.0000x reference)
//
#include <hip/hip_runtime.h>

#define D 128

// ---------------------------------------------------------------------------
// Kernel 1: z = h @ W (fp32, vector ALU — no fp32 MFMA on CDNA4), fused
// s_src = z @ attn[:128], s_dst = z @ attn[128:], plus zero-init of count[].
// Block = 256 threads = (tx:32 cols-of-4, ty:8 rows), 32 rows per block.
// W staged in LDS in two K-tiles of 64 (40KB LDS total).
// ---------------------------------------------------------------------------
#define FMA4(a, hc, wv) \
    a.x = fmaf(hc, wv.x, a.x); a.y = fmaf(hc, wv.y, a.y); \
    a.z = fmaf(hc, wv.z, a.z); a.w = fmaf(hc, wv.w, a.w);

__global__ __launch_bounds__(256) void gemm_fused_kernel(
    const float* __restrict__ h, const float* __restrict__ W,
    const float* __restrict__ attn,
    float* __restrict__ z, float* __restrict__ s_src, float* __restrict__ s_dst,
    int* __restrict__ count, int N)
{
    __shared__ float Wl[64][D];   // 32 KB
    __shared__ float hl[32][64];  // 8 KB
    const int tid = threadIdx.x;
    const int tx = tid & 31;      // column group: cols [4tx, 4tx+4)
    const int ty = tid >> 5;      // row group: rows ty, ty+8, ty+16, ty+24
    const int base = blockIdx.x * 32;

    float4 acc[4];
#pragma unroll
    for (int i = 0; i < 4; ++i) acc[i] = make_float4(0.f, 0.f, 0.f, 0.f);

    for (int kt = 0; kt < D; kt += 64) {
        // stage W[kt:kt+64, :] -> Wl (2048 float4 / 256 threads = 8 each)
#pragma unroll
        for (int i = 0; i < 8; ++i) {
            int j = tid + 256 * i;
            int row = j >> 5, c4 = (j & 31) * 4;
            *(float4*)&Wl[row][c4] = *(const float4*)&W[(size_t)(kt + row) * D + c4];
        }
        // stage h[base:base+32, kt:kt+64] -> hl (512 float4 / 256 = 2 each)
#pragma unroll
        for (int i = 0; i < 2; ++i) {
            int j = tid + 256 * i;
            int row = j >> 4, c4 = (j & 15) * 4;
            int r = base + row;
            float4 v = make_float4(0.f, 0.f, 0.f, 0.f);
            if (r < N) v = *(const float4*)&h[(size_t)r * D + kt + c4];
            *(float4*)&hl[row][c4] = v;
        }
        __syncthreads();
#pragma unroll
        for (int kk = 0; kk < 64; kk += 4) {
            float4 w0 = *(float4*)&Wl[kk + 0][tx * 4];
            float4 w1 = *(float4*)&Wl[kk + 1][tx * 4];
            float4 w2 = *(float4*)&Wl[kk + 2][tx * 4];
            float4 w3 = *(float4*)&Wl[kk + 3][tx * 4];
#pragma unroll
            for (int i = 0; i < 4; ++i) {
                float4 hv = *(float4*)&hl[ty + 8 * i][kk];
                FMA4(acc[i], hv.x, w0);
                FMA4(acc[i], hv.y, w1);
                FMA4(acc[i], hv.z, w2);
                FMA4(acc[i], hv.w, w3);
            }
        }
        __syncthreads();
    }

    // Epilogue: write z rows, reduce s_src/s_dst across the 32 tx lanes.
    const float4 aL = *(const float4*)&attn[tx * 4];
    const float4 aR = *(const float4*)&attn[D + tx * 4];
#pragma unroll
    for (int i = 0; i < 4; ++i) {
        int r = base + ty + 8 * i;
        float ps = acc[i].x * aL.x + acc[i].y * aL.y + acc[i].z * aL.z + acc[i].w * aL.w;
        float pd = acc[i].x * aR.x + acc[i].y * aR.y + acc[i].z * aR.z + acc[i].w * aR.w;
#pragma unroll
        for (int off = 16; off; off >>= 1) {
            ps += __shfl_down(ps, off, 32);
            pd += __shfl_down(pd, off, 32);
        }
        if (r < N) {
            *(float4*)&z[(size_t)r * D + tx * 4] = acc[i];
            if (tx == 0) { s_src[r] = ps; s_dst[r] = pd; count[r] = 0; }
        }
    }
}

// ---------------------------------------------------------------------------
// CSR build: count -> scan -> scatter (src|etype packed; src<65536, etype<512)
// ---------------------------------------------------------------------------
__global__ void count_kernel(const int* __restrict__ dst, int* __restrict__ count, int E)
{
    int i = blockIdx.x * blockDim.x + threadIdx.x;
    if (i < E) atomicAdd(&count[dst[i]], 1);
}

#define SCAN_T 1024
__global__ __launch_bounds__(SCAN_T) void scan_kernel(
    const int* __restrict__ count, int* __restrict__ offsets,
    int* __restrict__ cursor, int N)
{
    __shared__ int part[SCAN_T];
    const int t = threadIdx.x;
    const int C = (N + SCAN_T - 1) / SCAN_T;
    const int s = t * C;
    const int e = min(s + C, N);
    int sum = 0;
    for (int i = s; i < e; ++i) sum += count[i];
    part[t] = sum;
    __syncthreads();
    // Hillis-Steele inclusive scan over 1024 partials
    for (int off = 1; off < SCAN_T; off <<= 1) {
        int v = (t >= off) ? part[t - off] : 0;
        __syncthreads();
        part[t] += v;
        __syncthreads();
    }
    int run = (t == 0) ? 0 : part[t - 1];
    for (int i = s; i < e; ++i) {
        offsets[i] = run;
        cursor[i] = run;
        run += count[i];
    }
    if (t == SCAN_T - 1) offsets[N] = run;  // == E
}

__global__ void scatter_kernel(
    const int* __restrict__ src, const int* __restrict__ dst,
    const int* __restrict__ etype, int* __restrict__ cursor,
    int* __restrict__ csr_packed, int E)
{
    int i = blockIdx.x * blockDim.x + threadIdx.x;
    if (i < E) {
        int slot = atomicAdd(&cursor[dst[i]], 1);
        csr_packed[slot] = src[i] | (etype[i] << 16);
    }
}

// ---------------------------------------------------------------------------
// Kernel 5: one wave per dst node. Online softmax over incoming edges
// (64-edge chunks, lane-parallel logits, shuffle reductions) + serial
// per-edge broadcast and coalesced float2 accumulation of z[src] rows.
// No atomics, out written exactly once.
// ---------------------------------------------------------------------------
__global__ __launch_bounds__(256) void aggregate_kernel(
    const float* __restrict__ z, const float* __restrict__ s_src,
    const float* __restrict__ s_dst, const int* __restrict__ offsets,
    const int* __restrict__ csr_packed, const float* __restrict__ rel_emb,
    float* __restrict__ out, int N, int R)
{
    __shared__ float rel_l[128];
    const int tid = threadIdx.x;
    if (tid < R) rel_l[tid] = (tid == 0) ? 0.f : rel_emb[tid];  // padding_idx=0
    __syncthreads();

    const int lane = tid & 63;
    const int d = blockIdx.x * 4 + (tid >> 6);
    if (d >= N) return;

    const int start = offsets[d];
    const int end = offsets[d + 1];
    const float sdst = s_dst[d];

    float m = -INFINITY, l = 0.f;
    float2 acc = make_float2(0.f, 0.f);

    for (int base = start; base < end; base += 64) {
        const int idx = base + lane;
        const bool valid = idx < end;
        const int packed = valid ? csr_packed[idx] : 0;
        const int srcv = packed & 0xFFFF;
        const int et = packed >> 16;
        float ev = -INFINITY;
        if (valid) {
            float x = s_src[srcv] + sdst;
            ev = (x > 0.f) ? x : 0.01f * x;  // leaky_relu slope 0.01
        }
        // chunk max across the wave
        float cm = ev;
#pragma unroll
        for (int off = 32; off; off >>= 1) cm = fmaxf(cm, __shfl_xor(cm, off));
        const float newm = fmaxf(m, cm);
        const float scale = __expf(m - newm);  // 0 on first chunk (m=-inf)
        const float p = valid ? __expf(ev - newm) : 0.f;
        float ssum = p;
#pragma unroll
        for (int off = 32; off; off >>= 1) ssum += __shfl_xor(ssum, off);
        l = l * scale + ssum;
        acc.x *= scale;
        acc.y *= scale;
        m = newm;

        const float w = valid ? p * rel_l[et] : 0.f;
        const int nv = min(64, end - base);
        for (int j = 0; j < nv; ++j) {
            const float wj = __shfl(w, j);
            if (wj == 0.f) continue;           // wave-uniform skip (etype==0 etc.)
            const int sj = __shfl(srcv, j);
            const float2 zv = *(const float2*)(z + (size_t)sj * D + 2 * lane);
            acc.x = fmaf(wj, zv.x, acc.x);
            acc.y = fmaf(wj, zv.y, acc.y);
        }
    }

    const float inv = (l > 0.f) ? 1.0f / l : 0.f;  // no-edge nodes -> 0
    float2 res = make_float2(acc.x * inv, acc.y * inv);
    *(float2*)(out + (size_t)d * D + 2 * lane) = res;
}

// ---------------------------------------------------------------------------
extern "C" void kernel_launch(void* const* d_in, const int* in_sizes, int n_in,
                              void* d_out, int out_size, void* d_ws, size_t ws_size,
                              hipStream_t stream)
{
    const float* h    = (const float*)d_in[0];
    const float* W    = (const float*)d_in[1];
    const float* attn = (const float*)d_in[2];
    const float* rel  = (const float*)d_in[3];
    const int*   src  = (const int*)d_in[4];
    const int*   dst  = (const int*)d_in[5];
    const int*   et   = (const int*)d_in[6];
    float* out = (float*)d_out;

    const int N = in_sizes[0] / D;   // 50000
    const int E = in_sizes[4];       // 800000
    const int R = in_sizes[3];       // 100

    char* p = (char*)d_ws;
    auto alloc = [&](size_t bytes) {
        char* q = p;
        p += (bytes + 255) & ~(size_t)255;
        return q;
    };
    float* z       = (float*)alloc((size_t)N * D * sizeof(float));  // 25.6 MB
    float* ssrc    = (float*)alloc((size_t)N * sizeof(float));
    float* sdst    = (float*)alloc((size_t)N * sizeof(float));
    int*   count   = (int*)alloc((size_t)N * sizeof(int));
    int*   offsets = (int*)alloc((size_t)(N + 1) * sizeof(int));
    int*   cursor  = (int*)alloc((size_t)N * sizeof(int));
    int*   csr     = (int*)alloc((size_t)E * sizeof(int));          // 3.2 MB

    gemm_fused_kernel<<<(N + 31) / 32, 256, 0, stream>>>(h, W, attn, z, ssrc, sdst, count, N);
    count_kernel<<<(E + 255) / 256, 256, 0, stream>>>(dst, count, E);
    scan_kernel<<<1, SCAN_T, 0, stream>>>(count, offsets, cursor, N);
    scatter_kernel<<<(E + 255) / 256, 256, 0, stream>>>(src, dst, et, cursor, csr, E);
    aggregate_kernel<<<(N + 3) / 4, 256, 0, stream>>>(z, ssrc, sdst, offsets, csr, rel, out, N, R);
}

// Round 2
// 263.632 us; speedup vs baseline: 1.3990x; 1.3990x over previous
//
#include <hip/hip_runtime.h>

#define D 128

// ---------------------------------------------------------------------------
// Kernel 1: z = h @ W (fp32, vector ALU — no fp32 MFMA on CDNA4), fused
// s_src = z @ attn[:128], s_dst = z @ attn[128:], plus zero-init of count[].
// Block = 256 threads = (tx:32 cols-of-4, ty:8 rows), 32 rows per block.
// ---------------------------------------------------------------------------
#define FMA4(a, hc, wv) \
    a.x = fmaf(hc, wv.x, a.x); a.y = fmaf(hc, wv.y, a.y); \
    a.z = fmaf(hc, wv.z, a.z); a.w = fmaf(hc, wv.w, a.w);

__global__ __launch_bounds__(256) void gemm_fused_kernel(
    const float* __restrict__ h, const float* __restrict__ W,
    const float* __restrict__ attn,
    float* __restrict__ z, float* __restrict__ s_src, float* __restrict__ s_dst,
    int* __restrict__ count, int N)
{
    __shared__ float Wl[64][D];   // 32 KB
    __shared__ float hl[32][64];  // 8 KB
    const int tid = threadIdx.x;
    const int tx = tid & 31;      // column group: cols [4tx, 4tx+4)
    const int ty = tid >> 5;      // row group: rows ty, ty+8, ty+16, ty+24
    const int base = blockIdx.x * 32;

    float4 acc[4];
#pragma unroll
    for (int i = 0; i < 4; ++i) acc[i] = make_float4(0.f, 0.f, 0.f, 0.f);

    for (int kt = 0; kt < D; kt += 64) {
#pragma unroll
        for (int i = 0; i < 8; ++i) {
            int j = tid + 256 * i;
            int row = j >> 5, c4 = (j & 31) * 4;
            *(float4*)&Wl[row][c4] = *(const float4*)&W[(size_t)(kt + row) * D + c4];
        }
#pragma unroll
        for (int i = 0; i < 2; ++i) {
            int j = tid + 256 * i;
            int row = j >> 4, c4 = (j & 15) * 4;
            int r = base + row;
            float4 v = make_float4(0.f, 0.f, 0.f, 0.f);
            if (r < N) v = *(const float4*)&h[(size_t)r * D + kt + c4];
            *(float4*)&hl[row][c4] = v;
        }
        __syncthreads();
#pragma unroll
        for (int kk = 0; kk < 64; kk += 4) {
            float4 w0 = *(float4*)&Wl[kk + 0][tx * 4];
            float4 w1 = *(float4*)&Wl[kk + 1][tx * 4];
            float4 w2 = *(float4*)&Wl[kk + 2][tx * 4];
            float4 w3 = *(float4*)&Wl[kk + 3][tx * 4];
#pragma unroll
            for (int i = 0; i < 4; ++i) {
                float4 hv = *(float4*)&hl[ty + 8 * i][kk];
                FMA4(acc[i], hv.x, w0);
                FMA4(acc[i], hv.y, w1);
                FMA4(acc[i], hv.z, w2);
                FMA4(acc[i], hv.w, w3);
            }
        }
        __syncthreads();
    }

    const float4 aL = *(const float4*)&attn[tx * 4];
    const float4 aR = *(const float4*)&attn[D + tx * 4];
#pragma unroll
    for (int i = 0; i < 4; ++i) {
        int r = base + ty + 8 * i;
        float ps = acc[i].x * aL.x + acc[i].y * aL.y + acc[i].z * aL.z + acc[i].w * aL.w;
        float pd = acc[i].x * aR.x + acc[i].y * aR.y + acc[i].z * aR.z + acc[i].w * aR.w;
#pragma unroll
        for (int off = 16; off; off >>= 1) {
            ps += __shfl_down(ps, off, 32);
            pd += __shfl_down(pd, off, 32);
        }
        if (r < N) {
            *(float4*)&z[(size_t)r * D + tx * 4] = acc[i];
            if (tx == 0) { s_src[r] = ps; s_dst[r] = pd; count[r] = 0; }
        }
    }
}

// ---------------------------------------------------------------------------
// CSR build: count -> hierarchical scan (3 wide kernels) -> scatter
// ---------------------------------------------------------------------------
__global__ void count_kernel(const int* __restrict__ dst, int* __restrict__ count, int E)
{
    int i = blockIdx.x * blockDim.x + threadIdx.x;
    if (i < E) atomicAdd(&count[dst[i]], 1);
}

// scan1: per-block (2048-element) sums. 25 blocks for N=50000.
__global__ __launch_bounds__(256) void scan1_kernel(
    const int* __restrict__ count, int* __restrict__ bsum, int N)
{
    __shared__ int red[256];
    const int t = threadIdx.x;
    const int base = blockIdx.x * 2048 + t * 8;
    int s = 0;
    if (base + 8 <= N) {
        int4 a = *(const int4*)&count[base];
        int4 b = *(const int4*)&count[base + 4];
        s = a.x + a.y + a.z + a.w + b.x + b.y + b.z + b.w;
    } else {
        for (int i = 0; i < 8; ++i) if (base + i < N) s += count[base + i];
    }
    red[t] = s;
    __syncthreads();
#pragma unroll
    for (int off = 128; off; off >>= 1) {
        if (t < off) red[t] += red[t + off];
        __syncthreads();
    }
    if (t == 0) bsum[blockIdx.x] = red[0];
}

// scan2: one wave scans the <=64 block sums; writes exclusive block offsets
// and offsets[N] = E.
__global__ __launch_bounds__(64) void scan2_kernel(
    const int* __restrict__ bsum, int* __restrict__ boff,
    int* __restrict__ offsets, int nb, int N)
{
    const int t = threadIdx.x;
    int orig = (t < nb) ? bsum[t] : 0;
    int v = orig;
#pragma unroll
    for (int off = 1; off < 64; off <<= 1) {
        int u = __shfl_up(v, off);
        if (t >= off) v += u;
    }
    if (t < nb) boff[t] = v - orig;   // exclusive prefix
    if (t == 63) offsets[N] = v;      // total == E
}

// scan3: per-block local exclusive scan + block offset -> offsets/cursor.
__global__ __launch_bounds__(256) void scan3_kernel(
    const int* __restrict__ count, const int* __restrict__ boff,
    int* __restrict__ offsets, int* __restrict__ cursor, int N)
{
    __shared__ int red[256];
    const int t = threadIdx.x;
    const int base = blockIdx.x * 2048 + t * 8;
    int c[8];
    int s = 0;
#pragma unroll
    for (int i = 0; i < 8; ++i) {
        c[i] = (base + i < N) ? count[base + i] : 0;
        s += c[i];
    }
    red[t] = s;
    __syncthreads();
    for (int off = 1; off < 256; off <<= 1) {
        int u = (t >= off) ? red[t - off] : 0;
        __syncthreads();
        red[t] += u;
        __syncthreads();
    }
    int run = boff[blockIdx.x] + red[t] - s;  // exclusive prefix for this thread
#pragma unroll
    for (int i = 0; i < 8; ++i) {
        int idx = base + i;
        if (idx < N) { offsets[idx] = run; cursor[idx] = run; run += c[i]; }
    }
}

__global__ void scatter_kernel(
    const int* __restrict__ src, const int* __restrict__ dst,
    const int* __restrict__ etype, int* __restrict__ cursor,
    int* __restrict__ csr_packed, int E)
{
    int i = blockIdx.x * blockDim.x + threadIdx.x;
    if (i < E) {
        int slot = atomicAdd(&cursor[dst[i]], 1);
        csr_packed[slot] = src[i] | (etype[i] << 16);
    }
}

// ---------------------------------------------------------------------------
// Kernel 5: one wave per dst node. Online softmax over incoming edges
// (64-edge chunks, lane-parallel logits, shuffle reductions) + per-edge
// broadcast and coalesced float2 accumulation of z[src] rows, unrolled x2
// for load-latency hiding. No atomics, out written exactly once.
// ---------------------------------------------------------------------------
__global__ __launch_bounds__(256) void aggregate_kernel(
    const float* __restrict__ z, const float* __restrict__ s_src,
    const float* __restrict__ s_dst, const int* __restrict__ offsets,
    const int* __restrict__ csr_packed, const float* __restrict__ rel_emb,
    float* __restrict__ out, int N, int R)
{
    __shared__ float rel_l[128];
    const int tid = threadIdx.x;
    if (tid < R) rel_l[tid] = (tid == 0) ? 0.f : rel_emb[tid];  // padding_idx=0
    __syncthreads();

    const int lane = tid & 63;
    const int d = blockIdx.x * 4 + (tid >> 6);
    if (d >= N) return;

    const int start = offsets[d];
    const int end = offsets[d + 1];
    const float sdst = s_dst[d];

    float m = -INFINITY, l = 0.f;
    float2 acc = make_float2(0.f, 0.f);

    for (int base = start; base < end; base += 64) {
        const int idx = base + lane;
        const bool valid = idx < end;
        const int packed = valid ? csr_packed[idx] : 0;
        const int srcv = packed & 0xFFFF;
        const int et = packed >> 16;
        float ev = -INFINITY;
        if (valid) {
            float x = s_src[srcv] + sdst;
            ev = (x > 0.f) ? x : 0.01f * x;  // leaky_relu slope 0.01
        }
        float cm = ev;
#pragma unroll
        for (int off = 32; off; off >>= 1) cm = fmaxf(cm, __shfl_xor(cm, off));
        const float newm = fmaxf(m, cm);
        const float scale = __expf(m - newm);  // 0 on first chunk (m=-inf)
        const float p = valid ? __expf(ev - newm) : 0.f;
        float ssum = p;
#pragma unroll
        for (int off = 32; off; off >>= 1) ssum += __shfl_xor(ssum, off);
        l = l * scale + ssum;
        acc.x *= scale;
        acc.y *= scale;
        m = newm;

        const float w = valid ? p * rel_l[et] : 0.f;
        const int nv = min(64, end - base);
        int j = 0;
        for (; j + 1 < nv; j += 2) {
            const float w0 = __shfl(w, j);
            const float w1 = __shfl(w, j + 1);
            const int s0 = __shfl(srcv, j);
            const int s1 = __shfl(srcv, j + 1);
            const float2 z0 = *(const float2*)(z + (size_t)s0 * D + 2 * lane);
            const float2 z1 = *(const float2*)(z + (size_t)s1 * D + 2 * lane);
            acc.x = fmaf(w0, z0.x, acc.x);
            acc.y = fmaf(w0, z0.y, acc.y);
            acc.x = fmaf(w1, z1.x, acc.x);
            acc.y = fmaf(w1, z1.y, acc.y);
        }
        if (j < nv) {
            const float wj = __shfl(w, j);
            const int sj = __shfl(srcv, j);
            const float2 zv = *(const float2*)(z + (size_t)sj * D + 2 * lane);
            acc.x = fmaf(wj, zv.x, acc.x);
            acc.y = fmaf(wj, zv.y, acc.y);
        }
    }

    const float inv = (l > 0.f) ? 1.0f / l : 0.f;  // no-edge nodes -> 0
    float2 res = make_float2(acc.x * inv, acc.y * inv);
    *(float2*)(out + (size_t)d * D + 2 * lane) = res;
}

// ---------------------------------------------------------------------------
extern "C" void kernel_launch(void* const* d_in, const int* in_sizes, int n_in,
                              void* d_out, int out_size, void* d_ws, size_t ws_size,
                              hipStream_t stream)
{
    const float* h    = (const float*)d_in[0];
    const float* W    = (const float*)d_in[1];
    const float* attn = (const float*)d_in[2];
    const float* rel  = (const float*)d_in[3];
    const int*   src  = (const int*)d_in[4];
    const int*   dst  = (const int*)d_in[5];
    const int*   et   = (const int*)d_in[6];
    float* out = (float*)d_out;

    const int N = in_sizes[0] / D;   // 50000
    const int E = in_sizes[4];       // 800000
    const int R = in_sizes[3];       // 100

    char* p = (char*)d_ws;
    auto alloc = [&](size_t bytes) {
        char* q = p;
        p += (bytes + 255) & ~(size_t)255;
        return q;
    };
    float* z       = (float*)alloc((size_t)N * D * sizeof(float));  // 25.6 MB
    float* ssrc    = (float*)alloc((size_t)N * sizeof(float));
    float* sdst    = (float*)alloc((size_t)N * sizeof(float));
    int*   count   = (int*)alloc((size_t)N * sizeof(int));
    int*   offsets = (int*)alloc((size_t)(N + 1) * sizeof(int));
    int*   cursor  = (int*)alloc((size_t)N * sizeof(int));
    int*   csr     = (int*)alloc((size_t)E * sizeof(int));          // 3.2 MB
    const int nb   = (N + 2047) / 2048;                             // 25
    int*   bsum    = (int*)alloc((size_t)nb * sizeof(int));
    int*   boff    = (int*)alloc((size_t)nb * sizeof(int));

    gemm_fused_kernel<<<(N + 31) / 32, 256, 0, stream>>>(h, W, attn, z, ssrc, sdst, count, N);
    count_kernel<<<(E + 255) / 256, 256, 0, stream>>>(dst, count, E);
    scan1_kernel<<<nb, 256, 0, stream>>>(count, bsum, N);
    scan2_kernel<<<1, 64, 0, stream>>>(bsum, boff, offsets, nb, N);
    scan3_kernel<<<nb, 256, 0, stream>>>(count, boff, offsets, cursor, N);
    scatter_kernel<<<(E + 255) / 256, 256, 0, stream>>>(src, dst, et, cursor, csr, E);
    aggregate_kernel<<<(N + 3) / 4, 256, 0, stream>>>(z, ssrc, sdst, offsets, csr, rel, out, N, R);
}

// Round 3
// 240.396 us; speedup vs baseline: 1.5342x; 1.0967x over previous
//
#include <hip/hip_runtime.h>

#define D 128
#define GROWS 64

typedef __attribute__((ext_vector_type(8))) short short8;
typedef __attribute__((ext_vector_type(4))) float float4v;

// round-to-nearest-even fp32 -> bf16 (inputs are finite; no NaN handling needed)
__device__ __forceinline__ ushort f2bf(float x) {
    uint u = __float_as_uint(x);
    return (ushort)((u + 0x7FFFu + ((u >> 16) & 1u)) >> 16);
}

// ---------------------------------------------------------------------------
// Kernel 1: z = h @ W via bf16 MFMA (16x16x32), K=128 fully LDS-resident.
// Fused: s_src = z@attn[:128], s_dst = z@attn[128:], z written as bf16,
// and a grid-stride edge-count tail (count[] pre-zeroed by hipMemsetAsync).
// LDS: Wt (transposed, stride 136 to break bank conflicts) + h-tile + attn.
// Block 256 = 4 waves, 64 rows/block.
// ---------------------------------------------------------------------------
__global__ __launch_bounds__(256) void gemm_mfma_kernel(
    const float* __restrict__ h, const float* __restrict__ W,
    const float* __restrict__ attn, const int* __restrict__ dst,
    ushort* __restrict__ zb, float* __restrict__ s_src, float* __restrict__ s_dst,
    int* __restrict__ count, int N, int E, int nblocks)
{
    __shared__ ushort Wt[128 * 136];   // Wt[n*136 + k], bf16, 34816 B
    __shared__ ushort ht[GROWS * 136]; // ht[r*136 + k], bf16, 17408 B
    __shared__ float attnL[2 * D];     // 1024 B
    const int tid = threadIdx.x;
    const int base = blockIdx.x * GROWS;

    if (tid < 2 * D) attnL[tid] = attn[tid];

    // stage W transposed fp32->bf16: 16384 elements, coalesced reads
#pragma unroll
    for (int it = 0; it < 64; ++it) {
        int idx = it * 256 + tid;
        int k = idx >> 7, n = idx & 127;
        Wt[n * 136 + k] = f2bf(W[idx]);
    }
    // stage h rows [base, base+64) fp32->bf16, float4 coalesced reads
#pragma unroll
    for (int it = 0; it < 8; ++it) {
        int idx = it * 256 + tid;
        int r = idx >> 5, c4 = (idx & 31) * 4;
        float4 v = make_float4(0.f, 0.f, 0.f, 0.f);
        if (base + r < N) v = *(const float4*)&h[(size_t)(base + r) * D + c4];
        ushort* p = &ht[r * 136 + c4];
        p[0] = f2bf(v.x); p[1] = f2bf(v.y); p[2] = f2bf(v.z); p[3] = f2bf(v.w);
    }
    __syncthreads();

    const int lane = tid & 63;
    const int wave = tid >> 6;
    const int col = lane & 15;   // MFMA n / C-col
    const int quad = lane >> 4;  // MFMA k-group / C-row-group
    const int wm = wave * 16;    // wave's row base within block

    float4v acc[8];
#pragma unroll
    for (int nt = 0; nt < 8; ++nt) acc[nt] = (float4v)(0.f);

    // A[m=lane&15][k=quad*8+j], B[k=quad*8+j][n=lane&15] (m89-verified layout)
#pragma unroll
    for (int kc = 0; kc < 128; kc += 32) {
        short8 a = *(const short8*)&ht[(wm + col) * 136 + kc + quad * 8];
#pragma unroll
        for (int nt = 0; nt < 8; ++nt) {
            short8 b = *(const short8*)&Wt[(nt * 16 + col) * 136 + kc + quad * 8];
            acc[nt] = __builtin_amdgcn_mfma_f32_16x16x32_bf16(a, b, acc[nt], 0, 0, 0);
        }
    }

    // Epilogue: C/D layout col=lane&15, row=quad*4+reg (m89/m91-verified).
    float ps[4] = {0.f, 0.f, 0.f, 0.f}, pd[4] = {0.f, 0.f, 0.f, 0.f};
#pragma unroll
    for (int nt = 0; nt < 8; ++nt) {
        float aL = attnL[nt * 16 + col];
        float aR = attnL[D + nt * 16 + col];
#pragma unroll
        for (int reg = 0; reg < 4; ++reg) {
            float v = acc[nt][reg];
            ps[reg] = fmaf(v, aL, ps[reg]);
            pd[reg] = fmaf(v, aR, pd[reg]);
            int grow = base + wm + quad * 4 + reg;
            if (grow < N) zb[(size_t)grow * D + nt * 16 + col] = f2bf(v);
        }
    }
#pragma unroll
    for (int reg = 0; reg < 4; ++reg) {
#pragma unroll
        for (int off = 1; off < 16; off <<= 1) {
            ps[reg] += __shfl_xor(ps[reg], off);
            pd[reg] += __shfl_xor(pd[reg], off);
        }
        int grow = base + wm + quad * 4 + reg;
        if (col == 0 && grow < N) { s_src[grow] = ps[reg]; s_dst[grow] = pd[reg]; }
    }

    // fused edge counting
    for (int i = blockIdx.x * 256 + tid; i < E; i += nblocks * 256)
        atomicAdd(&count[dst[i]], 1);
}

// ---------------------------------------------------------------------------
// CSR build: scan1 (block sums) -> scan3 (inline partial-scan + local scan)
// -> scatter. 2048 counts per block, 25 blocks for N=50000.
// ---------------------------------------------------------------------------
__global__ __launch_bounds__(256) void scan1_kernel(
    const int* __restrict__ count, int* __restrict__ bsum, int N)
{
    __shared__ int red[256];
    const int t = threadIdx.x;
    const int base = blockIdx.x * 2048 + t * 8;
    int s = 0;
    if (base + 8 <= N) {
        int4 a = *(const int4*)&count[base];
        int4 b = *(const int4*)&count[base + 4];
        s = a.x + a.y + a.z + a.w + b.x + b.y + b.z + b.w;
    } else {
        for (int i = 0; i < 8; ++i) if (base + i < N) s += count[base + i];
    }
    red[t] = s;
    __syncthreads();
#pragma unroll
    for (int off = 128; off; off >>= 1) {
        if (t < off) red[t] += red[t + off];
        __syncthreads();
    }
    if (t == 0) bsum[blockIdx.x] = red[0];
}

__global__ __launch_bounds__(256) void scan3_kernel(
    const int* __restrict__ count, const int* __restrict__ bsum,
    int* __restrict__ offsets, int* __restrict__ cursor, int N, int E)
{
    __shared__ int red[256];
    const int t = threadIdx.x;
    // block offset: redundant per-thread sum of <=25 partials (L2-cached)
    int pre = 0;
    for (int b = 0; b < (int)blockIdx.x; ++b) pre += bsum[b];
    const int base = blockIdx.x * 2048 + t * 8;
    int c[8];
    int s = 0;
#pragma unroll
    for (int i = 0; i < 8; ++i) {
        c[i] = (base + i < N) ? count[base + i] : 0;
        s += c[i];
    }
    red[t] = s;
    __syncthreads();
    for (int off = 1; off < 256; off <<= 1) {
        int u = (t >= off) ? red[t - off] : 0;
        __syncthreads();
        red[t] += u;
        __syncthreads();
    }
    int run = pre + red[t] - s;  // exclusive prefix for this thread's 8 counts
#pragma unroll
    for (int i = 0; i < 8; ++i) {
        int idx = base + i;
        if (idx < N) { offsets[idx] = run; cursor[idx] = run; run += c[i]; }
    }
    if (blockIdx.x == 0 && t == 0) offsets[N] = E;
}

__global__ void scatter_kernel(
    const int* __restrict__ src, const int* __restrict__ dst,
    const int* __restrict__ etype, int* __restrict__ cursor,
    int* __restrict__ csr_packed, int E)
{
    int i = blockIdx.x * blockDim.x + threadIdx.x;
    if (i < E) {
        int slot = atomicAdd(&cursor[dst[i]], 1);
        csr_packed[slot] = src[i] | (etype[i] << 16);
    }
}

// ---------------------------------------------------------------------------
// Kernel 5: one wave per dst node; online softmax + weighted bf16-z gather.
// Each lane loads one packed uint (2 bf16 cols) per edge -> 256 B/edge row.
// ---------------------------------------------------------------------------
__global__ __launch_bounds__(256) void aggregate_kernel(
    const uint* __restrict__ zb32, const float* __restrict__ s_src,
    const float* __restrict__ s_dst, const int* __restrict__ offsets,
    const int* __restrict__ csr_packed, const float* __restrict__ rel_emb,
    float* __restrict__ out, int N, int R)
{
    __shared__ float rel_l[128];
    const int tid = threadIdx.x;
    if (tid < R) rel_l[tid] = (tid == 0) ? 0.f : rel_emb[tid];  // padding_idx=0
    __syncthreads();

    const int lane = tid & 63;
    const int d = blockIdx.x * 4 + (tid >> 6);
    if (d >= N) return;

    const int start = offsets[d];
    const int end = offsets[d + 1];
    const float sdst = s_dst[d];

    float m = -INFINITY, l = 0.f;
    float2 acc = make_float2(0.f, 0.f);

    for (int base = start; base < end; base += 64) {
        const int idx = base + lane;
        const bool valid = idx < end;
        const int packed = valid ? csr_packed[idx] : 0;
        const int srcv = packed & 0xFFFF;
        const int et = packed >> 16;
        float ev = -INFINITY;
        if (valid) {
            float x = s_src[srcv] + sdst;
            ev = (x > 0.f) ? x : 0.01f * x;  // leaky_relu slope 0.01
        }
        float cm = ev;
#pragma unroll
        for (int off = 32; off; off >>= 1) cm = fmaxf(cm, __shfl_xor(cm, off));
        const float newm = fmaxf(m, cm);
        const float scale = __expf(m - newm);  // 0 on first chunk (m=-inf)
        const float p = valid ? __expf(ev - newm) : 0.f;
        float ssum = p;
#pragma unroll
        for (int off = 32; off; off >>= 1) ssum += __shfl_xor(ssum, off);
        l = l * scale + ssum;
        acc.x *= scale;
        acc.y *= scale;
        m = newm;

        const float w = valid ? p * rel_l[et] : 0.f;
        const int nv = min(64, end - base);
        int j = 0;
        for (; j + 1 < nv; j += 2) {
            const float w0 = __shfl(w, j);
            const float w1 = __shfl(w, j + 1);
            const int s0 = __shfl(srcv, j);
            const int s1 = __shfl(srcv, j + 1);
            const uint u0 = zb32[(size_t)s0 * 64 + lane];
            const uint u1 = zb32[(size_t)s1 * 64 + lane];
            acc.x = fmaf(w0, __uint_as_float(u0 << 16), acc.x);
            acc.y = fmaf(w0, __uint_as_float(u0 & 0xFFFF0000u), acc.y);
            acc.x = fmaf(w1, __uint_as_float(u1 << 16), acc.x);
            acc.y = fmaf(w1, __uint_as_float(u1 & 0xFFFF0000u), acc.y);
        }
        if (j < nv) {
            const float wj = __shfl(w, j);
            const int sj = __shfl(srcv, j);
            const uint u = zb32[(size_t)sj * 64 + lane];
            acc.x = fmaf(wj, __uint_as_float(u << 16), acc.x);
            acc.y = fmaf(wj, __uint_as_float(u & 0xFFFF0000u), acc.y);
        }
    }

    const float inv = (l > 0.f) ? 1.0f / l : 0.f;  // no-edge nodes -> 0
    float2 res = make_float2(acc.x * inv, acc.y * inv);
    *(float2*)(out + (size_t)d * D + 2 * lane) = res;
}

// ---------------------------------------------------------------------------
extern "C" void kernel_launch(void* const* d_in, const int* in_sizes, int n_in,
                              void* d_out, int out_size, void* d_ws, size_t ws_size,
                              hipStream_t stream)
{
    const float* h    = (const float*)d_in[0];
    const float* W    = (const float*)d_in[1];
    const float* attn = (const float*)d_in[2];
    const float* rel  = (const float*)d_in[3];
    const int*   src  = (const int*)d_in[4];
    const int*   dst  = (const int*)d_in[5];
    const int*   et   = (const int*)d_in[6];
    float* out = (float*)d_out;

    const int N = in_sizes[0] / D;   // 50000
    const int E = in_sizes[4];       // 800000
    const int R = in_sizes[3];       // 100

    char* p = (char*)d_ws;
    auto alloc = [&](size_t bytes) {
        char* q = p;
        p += (bytes + 255) & ~(size_t)255;
        return q;
    };
    ushort* zb     = (ushort*)alloc((size_t)N * D * sizeof(ushort));  // 12.8 MB
    float* ssrc    = (float*)alloc((size_t)N * sizeof(float));
    float* sdst    = (float*)alloc((size_t)N * sizeof(float));
    int*   count   = (int*)alloc((size_t)N * sizeof(int));
    int*   offsets = (int*)alloc((size_t)(N + 1) * sizeof(int));
    int*   cursor  = (int*)alloc((size_t)N * sizeof(int));
    int*   csr     = (int*)alloc((size_t)E * sizeof(int));            // 3.2 MB
    const int nb   = (N + 2047) / 2048;                               // 25
    int*   bsum    = (int*)alloc((size_t)nb * sizeof(int));

    const int gblocks = (N + GROWS - 1) / GROWS;  // 782

    hipMemsetAsync(count, 0, (size_t)N * sizeof(int), stream);
    gemm_mfma_kernel<<<gblocks, 256, 0, stream>>>(h, W, attn, dst, zb, ssrc, sdst,
                                                  count, N, E, gblocks);
    scan1_kernel<<<nb, 256, 0, stream>>>(count, bsum, N);
    scan3_kernel<<<nb, 256, 0, stream>>>(count, bsum, offsets, cursor, N, E);
    scatter_kernel<<<(E + 255) / 256, 256, 0, stream>>>(src, dst, et, cursor, csr, E);
    aggregate_kernel<<<(N + 3) / 4, 256, 0, stream>>>((const uint*)zb, ssrc, sdst,
                                                      offsets, csr, rel, out, N, R);
}

// Round 4
// 204.526 us; speedup vs baseline: 1.8033x; 1.1754x over previous
//
#include <hip/hip_runtime.h>

#define D 128
#define GROWS 64

typedef __attribute__((ext_vector_type(8))) short short8;
typedef __attribute__((ext_vector_type(4))) float float4v;

// round-to-nearest-even fp32 -> bf16 (inputs are finite; no NaN handling needed)
__device__ __forceinline__ ushort f2bf(float x) {
    uint u = __float_as_uint(x);
    return (ushort)((u + 0x7FFFu + ((u >> 16) & 1u)) >> 16);
}

// ---------------------------------------------------------------------------
// Kernel 0: one-time W convert+transpose: Wtg[n*128+k] = bf16(W[k*128+n]).
// 64 KB output, L1/L2-resident for the GEMM.
// ---------------------------------------------------------------------------
__global__ __launch_bounds__(256) void convW_kernel(
    const float* __restrict__ W, ushort* __restrict__ Wtg)
{
    int idx = blockIdx.x * 256 + threadIdx.x;  // 16384 total
    int k = idx >> 7, n = idx & 127;
    Wtg[n * 128 + k] = f2bf(W[idx]);
}

// ---------------------------------------------------------------------------
// Kernel 1: z = h @ W via bf16 MFMA (16x16x32). B-fragments read directly
// from global Wtg (32 KB -> L1-hot). LDS holds only the h-tile (17 KB,
// stride 136 = conflict-minimal) which is reused to stage the bf16 z-tile
// for fully-coalesced uint4 writeback. Fused: s_src/s_dst epilogue and the
// SINGLE random-atomic pass (count + per-edge rank).
// ---------------------------------------------------------------------------
__global__ __launch_bounds__(256) void gemm_mfma_kernel(
    const float* __restrict__ h, const ushort* __restrict__ Wtg,
    const float* __restrict__ attn, const int* __restrict__ dst,
    ushort* __restrict__ zb, float* __restrict__ s_src, float* __restrict__ s_dst,
    int* __restrict__ count, int* __restrict__ rank, int N, int E, int nblocks)
{
    __shared__ ushort ht[GROWS * 136];  // 17408 B; h-tile, then z-tile
    const int tid = threadIdx.x;
    const int base = blockIdx.x * GROWS;

    // stage h rows [base, base+64) fp32 -> bf16 (float4 reads, ushort4 writes)
#pragma unroll
    for (int it = 0; it < 8; ++it) {
        int idx = it * 256 + tid;
        int r = idx >> 5, c4 = (idx & 31) * 4;
        float4 v = make_float4(0.f, 0.f, 0.f, 0.f);
        if (base + r < N) v = *(const float4*)&h[(size_t)(base + r) * D + c4];
        ushort4 u = make_ushort4(f2bf(v.x), f2bf(v.y), f2bf(v.z), f2bf(v.w));
        *(ushort4*)&ht[r * 136 + c4] = u;
    }
    __syncthreads();

    const int lane = tid & 63;
    const int wave = tid >> 6;
    const int col = lane & 15;   // MFMA m/n index
    const int quad = lane >> 4;  // MFMA k-group
    const int wm = wave * 16;    // wave's 16-row tile within block

    float4v acc[8];
#pragma unroll
    for (int nt = 0; nt < 8; ++nt) acc[nt] = (float4v)(0.f);

    // A[m=col][k=quad*8+j] from LDS; B[k][n=col] from global Wtg (L1-hot).
#pragma unroll 1
    for (int kc = 0; kc < 128; kc += 32) {
        short8 a = *(const short8*)&ht[(wm + col) * 136 + kc + quad * 8];
#pragma unroll
        for (int nt = 0; nt < 8; ++nt) {
            short8 b = *(const short8*)&Wtg[(nt * 16 + col) * 128 + kc + quad * 8];
            acc[nt] = __builtin_amdgcn_mfma_f32_16x16x32_bf16(a, b, acc[nt], 0, 0, 0);
        }
    }

    // Epilogue: C/D layout col=lane&15, row=quad*4+reg (m89/m91-verified).
    float ps[4] = {0.f, 0.f, 0.f, 0.f}, pd[4] = {0.f, 0.f, 0.f, 0.f};
#pragma unroll
    for (int nt = 0; nt < 8; ++nt) {
        float aL = attn[nt * 16 + col];
        float aR = attn[D + nt * 16 + col];
#pragma unroll
        for (int reg = 0; reg < 4; ++reg) {
            float v = acc[nt][reg];
            ps[reg] = fmaf(v, aL, ps[reg]);
            pd[reg] = fmaf(v, aR, pd[reg]);
            // z-tile into LDS (rows [wm,wm+16) are wave-private)
            ht[(wm + quad * 4 + reg) * 136 + nt * 16 + col] = f2bf(v);
        }
    }
#pragma unroll
    for (int reg = 0; reg < 4; ++reg) {
#pragma unroll
        for (int off = 1; off < 16; off <<= 1) {
            ps[reg] += __shfl_xor(ps[reg], off);
            pd[reg] += __shfl_xor(pd[reg], off);
        }
        int grow = base + wm + quad * 4 + reg;
        if (col == 0 && grow < N) { s_src[grow] = ps[reg]; s_dst[grow] = pd[reg]; }
    }
    __syncthreads();

    // coalesced z writeback: 64 rows x 16 uint4 chunks = 1024 chunks
#pragma unroll
    for (int it = 0; it < 4; ++it) {
        int idx = it * 256 + tid;
        int r = idx >> 4, c8 = idx & 15;
        if (base + r < N)
            *(uint4*)&zb[(size_t)(base + r) * D + c8 * 8] = *(uint4*)&ht[r * 136 + c8 * 8];
    }

    // the ONE random-atomic pass: degree count + per-edge rank within dst
    for (int i = blockIdx.x * 256 + tid; i < E; i += nblocks * 256)
        rank[i] = atomicAdd(&count[dst[i]], 1);
}

// ---------------------------------------------------------------------------
// CSR offsets: scan1 (block sums) -> scan3 (redundant partial-sum + local scan)
// ---------------------------------------------------------------------------
__global__ __launch_bounds__(256) void scan1_kernel(
    const int* __restrict__ count, int* __restrict__ bsum, int N)
{
    __shared__ int red[256];
    const int t = threadIdx.x;
    const int base = blockIdx.x * 2048 + t * 8;
    int s = 0;
    if (base + 8 <= N) {
        int4 a = *(const int4*)&count[base];
        int4 b = *(const int4*)&count[base + 4];
        s = a.x + a.y + a.z + a.w + b.x + b.y + b.z + b.w;
    } else {
        for (int i = 0; i < 8; ++i) if (base + i < N) s += count[base + i];
    }
    red[t] = s;
    __syncthreads();
#pragma unroll
    for (int off = 128; off; off >>= 1) {
        if (t < off) red[t] += red[t + off];
        __syncthreads();
    }
    if (t == 0) bsum[blockIdx.x] = red[0];
}

__global__ __launch_bounds__(256) void scan3_kernel(
    const int* __restrict__ count, const int* __restrict__ bsum,
    int* __restrict__ offsets, int N, int E)
{
    __shared__ int red[256];
    const int t = threadIdx.x;
    int pre = 0;
    for (int b = 0; b < (int)blockIdx.x; ++b) pre += bsum[b];
    const int base = blockIdx.x * 2048 + t * 8;
    int c[8];
    int s = 0;
#pragma unroll
    for (int i = 0; i < 8; ++i) {
        c[i] = (base + i < N) ? count[base + i] : 0;
        s += c[i];
    }
    red[t] = s;
    __syncthreads();
    for (int off = 1; off < 256; off <<= 1) {
        int u = (t >= off) ? red[t - off] : 0;
        __syncthreads();
        red[t] += u;
        __syncthreads();
    }
    int run = pre + red[t] - s;
#pragma unroll
    for (int i = 0; i < 8; ++i) {
        int idx = base + i;
        if (idx < N) { offsets[idx] = run; run += c[i]; }
    }
    if (blockIdx.x == 0 && t == 0) offsets[N] = E;
}

// ---------------------------------------------------------------------------
// Atomic-free scatter: slot = offsets[dst] + rank. Plain cacheable traffic.
// ---------------------------------------------------------------------------
__global__ void scatter_kernel(
    const int* __restrict__ src, const int* __restrict__ dst,
    const int* __restrict__ etype, const int* __restrict__ rank,
    const int* __restrict__ offsets, int* __restrict__ csr_packed, int E)
{
    int i = blockIdx.x * blockDim.x + threadIdx.x;
    if (i < E)
        csr_packed[offsets[dst[i]] + rank[i]] = src[i] | (etype[i] << 16);
}

// ---------------------------------------------------------------------------
// Kernel 5: one wave per dst node; online softmax + weighted bf16-z gather.
// Each lane loads one packed uint (2 bf16 cols) per edge -> 256 B/edge row.
// ---------------------------------------------------------------------------
__global__ __launch_bounds__(256) void aggregate_kernel(
    const uint* __restrict__ zb32, const float* __restrict__ s_src,
    const float* __restrict__ s_dst, const int* __restrict__ offsets,
    const int* __restrict__ csr_packed, const float* __restrict__ rel_emb,
    float* __restrict__ out, int N, int R)
{
    __shared__ float rel_l[128];
    const int tid = threadIdx.x;
    if (tid < R) rel_l[tid] = (tid == 0) ? 0.f : rel_emb[tid];  // padding_idx=0
    __syncthreads();

    const int lane = tid & 63;
    const int d = blockIdx.x * 4 + (tid >> 6);
    if (d >= N) return;

    const int start = offsets[d];
    const int end = offsets[d + 1];
    const float sdst = s_dst[d];

    float m = -INFINITY, l = 0.f;
    float2 acc = make_float2(0.f, 0.f);

    for (int base = start; base < end; base += 64) {
        const int idx = base + lane;
        const bool valid = idx < end;
        const int packed = valid ? csr_packed[idx] : 0;
        const int srcv = packed & 0xFFFF;
        const int et = packed >> 16;
        float ev = -INFINITY;
        if (valid) {
            float x = s_src[srcv] + sdst;
            ev = (x > 0.f) ? x : 0.01f * x;  // leaky_relu slope 0.01
        }
        float cm = ev;
#pragma unroll
        for (int off = 32; off; off >>= 1) cm = fmaxf(cm, __shfl_xor(cm, off));
        const float newm = fmaxf(m, cm);
        const float scale = __expf(m - newm);  // 0 on first chunk (m=-inf)
        const float p = valid ? __expf(ev - newm) : 0.f;
        float ssum = p;
#pragma unroll
        for (int off = 32; off; off >>= 1) ssum += __shfl_xor(ssum, off);
        l = l * scale + ssum;
        acc.x *= scale;
        acc.y *= scale;
        m = newm;

        const float w = valid ? p * rel_l[et] : 0.f;
        const int nv = min(64, end - base);
        int j = 0;
        for (; j + 1 < nv; j += 2) {
            const float w0 = __shfl(w, j);
            const float w1 = __shfl(w, j + 1);
            const int s0 = __shfl(srcv, j);
            const int s1 = __shfl(srcv, j + 1);
            const uint u0 = zb32[(size_t)s0 * 64 + lane];
            const uint u1 = zb32[(size_t)s1 * 64 + lane];
            acc.x = fmaf(w0, __uint_as_float(u0 << 16), acc.x);
            acc.y = fmaf(w0, __uint_as_float(u0 & 0xFFFF0000u), acc.y);
            acc.x = fmaf(w1, __uint_as_float(u1 << 16), acc.x);
            acc.y = fmaf(w1, __uint_as_float(u1 & 0xFFFF0000u), acc.y);
        }
        if (j < nv) {
            const float wj = __shfl(w, j);
            const int sj = __shfl(srcv, j);
            const uint u = zb32[(size_t)sj * 64 + lane];
            acc.x = fmaf(wj, __uint_as_float(u << 16), acc.x);
            acc.y = fmaf(wj, __uint_as_float(u & 0xFFFF0000u), acc.y);
        }
    }

    const float inv = (l > 0.f) ? 1.0f / l : 0.f;  // no-edge nodes -> 0
    float2 res = make_float2(acc.x * inv, acc.y * inv);
    *(float2*)(out + (size_t)d * D + 2 * lane) = res;
}

// ---------------------------------------------------------------------------
extern "C" void kernel_launch(void* const* d_in, const int* in_sizes, int n_in,
                              void* d_out, int out_size, void* d_ws, size_t ws_size,
                              hipStream_t stream)
{
    const float* h    = (const float*)d_in[0];
    const float* W    = (const float*)d_in[1];
    const float* attn = (const float*)d_in[2];
    const float* rel  = (const float*)d_in[3];
    const int*   src  = (const int*)d_in[4];
    const int*   dst  = (const int*)d_in[5];
    const int*   et   = (const int*)d_in[6];
    float* out = (float*)d_out;

    const int N = in_sizes[0] / D;   // 50000
    const int E = in_sizes[4];       // 800000
    const int R = in_sizes[3];       // 100

    char* p = (char*)d_ws;
    auto alloc = [&](size_t bytes) {
        char* q = p;
        p += (bytes + 255) & ~(size_t)255;
        return q;
    };
    ushort* zb     = (ushort*)alloc((size_t)N * D * sizeof(ushort));  // 12.8 MB
    ushort* Wtg    = (ushort*)alloc((size_t)D * D * sizeof(ushort));  // 32 KB
    float* ssrc    = (float*)alloc((size_t)N * sizeof(float));
    float* sdst    = (float*)alloc((size_t)N * sizeof(float));
    int*   count   = (int*)alloc((size_t)N * sizeof(int));
    int*   offsets = (int*)alloc((size_t)(N + 1) * sizeof(int));
    int*   rank    = (int*)alloc((size_t)E * sizeof(int));            // 3.2 MB
    int*   csr     = (int*)alloc((size_t)E * sizeof(int));            // 3.2 MB
    const int nb   = (N + 2047) / 2048;                               // 25
    int*   bsum    = (int*)alloc((size_t)nb * sizeof(int));

    const int gblocks = (N + GROWS - 1) / GROWS;  // 782

    hipMemsetAsync(count, 0, (size_t)N * sizeof(int), stream);
    convW_kernel<<<64, 256, 0, stream>>>(W, Wtg);
    gemm_mfma_kernel<<<gblocks, 256, 0, stream>>>(h, Wtg, attn, dst, zb, ssrc, sdst,
                                                  count, rank, N, E, gblocks);
    scan1_kernel<<<nb, 256, 0, stream>>>(count, bsum, N);
    scan3_kernel<<<nb, 256, 0, stream>>>(count, bsum, offsets, N, E);
    scatter_kernel<<<(E + 255) / 256, 256, 0, stream>>>(src, dst, et, rank, offsets, csr, E);
    aggregate_kernel<<<(N + 3) / 4, 256, 0, stream>>>((const uint*)zb, ssrc, sdst,
                                                      offsets, csr, rel, out, N, R);
}